// Round 1
// baseline (199.151 us; speedup 1.0000x reference)
//
#include <hip/hip_runtime.h>
#include <stdint.h>
#include <math.h>

#define KDIM 2304   // 9 * 256

typedef __attribute__((ext_vector_type(8))) short bf16x8;
typedef __attribute__((ext_vector_type(4))) float f32x4;

__device__ inline unsigned short f2bf(float f) {
  union { float f; unsigned int u; } v; v.f = f;
  unsigned int u = v.u;
  unsigned int r = (u + 0x7FFFu + ((u >> 16) & 1u)) >> 16;
  return (unsigned short)r;
}
__device__ inline float bf2f(unsigned short h) {
  union { unsigned int u; float f; } v; v.u = ((unsigned int)h) << 16;
  return v.f;
}

__device__ inline void gl2lds16(const void* g, void* l) {
  __builtin_amdgcn_global_load_lds((const __attribute__((address_space(1))) void*)g,
                                   (__attribute__((address_space(3))) void*)l,
                                   16, 0, 0);
}

// ---------------------------------------------------------------------------
// Kernel 1: x (B,C,H,W) fp32 -> xTb (B,H,W,C) bf16
// ---------------------------------------------------------------------------
__global__ __launch_bounds__(256) void k_transpose(const float* __restrict__ x,
                                                   unsigned short* __restrict__ xTb) {
  __shared__ float tile[32][33];
  int t = threadIdx.x;
  int tx = t & 31, ty = t >> 5;            // ty in [0,8)
  int p0 = blockIdx.x * 32;                // spatial (h*64+w) tile
  int c0 = blockIdx.y * 32;                // channel tile
  int b  = blockIdx.z;
  const float* xb = x + ((size_t)b << 20); // 256*4096
#pragma unroll
  for (int i = 0; i < 4; ++i) {
    int c = c0 + ty + i * 8;
    tile[ty + i * 8][tx] = xb[((size_t)c << 12) + p0 + tx];
  }
  __syncthreads();
  unsigned short* ob = xTb + ((size_t)b << 20);
#pragma unroll
  for (int i = 0; i < 4; ++i) {
    int p = p0 + ty + i * 8;
    ob[(((size_t)p) << 8) + c0 + tx] = f2bf(tile[tx][ty + i * 8]);
  }
}

// ---------------------------------------------------------------------------
// Kernel 2: weight prep.
//  Wb[o][k*256+c]  = bf16(dcn_w[o][c][k])        (256 x 2304)
//  Wob[ch][k*256+c] = bf16(offset_w[ch][c][k])   (32 x 2304, ch>=27 -> 0)
//  zp = 128 zero bf16 (OOB redirect page)
// ---------------------------------------------------------------------------
__global__ __launch_bounds__(256) void k_wprep(const float* __restrict__ dcn_w,
                                               const float* __restrict__ offset_w,
                                               unsigned short* __restrict__ Wb,
                                               unsigned short* __restrict__ Wob,
                                               unsigned short* __restrict__ zp) {
  int gid = blockIdx.x * 256 + threadIdx.x;
  const int N1 = 256 * KDIM;
  const int N2 = 32 * KDIM;
  if (gid < N1) {
    int o = gid / KDIM, k = gid % KDIM;
    int kidx = k >> 8, c = k & 255;
    Wb[gid] = f2bf(dcn_w[((size_t)(o * 256 + c)) * 9 + kidx]);
  } else if (gid < N1 + N2) {
    int g = gid - N1;
    int ch = g / KDIM, k = g % KDIM;
    int kidx = k >> 8, c = k & 255;
    Wob[g] = (ch < 27) ? f2bf(offset_w[((size_t)(ch * 256 + c)) * 9 + kidx])
                       : (unsigned short)0;
  } else if (gid < N1 + N2 + 128) {
    zp[gid - N1 - N2] = 0;
  }
}

// ---------------------------------------------------------------------------
// Kernel 3: offset conv as MFMA GEMM with implicit im2col.
//  O2[bhw][32] = sum_k Patch[bhw][k] * Wob[ch][k]
//  Tile: BM=128 (bhw) x BN=32 (ch) x BK=32. Grid: 128 blocks, 256 thr.
// ---------------------------------------------------------------------------
__global__ __launch_bounds__(256) void k_offs_gemm(const unsigned short* __restrict__ xTb,
                                                   const unsigned short* __restrict__ Wob,
                                                   const unsigned short* __restrict__ zp,
                                                   float* __restrict__ O2) {
  __shared__ unsigned short As[128 * 32];
  __shared__ unsigned short Bs[32 * 32];
  int t = threadIdx.x;
  int wv = t >> 6, lane = t & 63;
  int n0 = blockIdx.x * 128;
  int r0 = t >> 2, coff = (t & 3) * 8;

  int rowA0 = n0 + r0;
  int rowA1 = n0 + r0 + 64;
  int b0_ = rowA0 >> 12, hw0 = rowA0 & 4095, h0 = hw0 >> 6, w0 = hw0 & 63;
  int b1_ = rowA1 >> 12, hw1 = rowA1 & 4095, h1 = hw1 >> 6, w1 = hw1 & 63;

  f32x4 acc[2][2] = {};
  char* AsB = (char*)As;
  char* BsB = (char*)Bs;

  for (int kt = 0; kt < 72; ++kt) {
    int k0 = kt * 32;
    int kidx = k0 >> 8, c0 = k0 & 255;
    int di = kidx / 3 - 1, dj = kidx % 3 - 1;
    {
      int y = h0 + di, xx = w0 + dj;
      const unsigned short* g = (y >= 0 && y < 64 && xx >= 0 && xx < 64)
          ? xTb + (((((size_t)b0_) << 12) + (y << 6) + xx) << 8) + c0 + coff
          : zp;
      gl2lds16(g, AsB + wv * 1024);
      int y1 = h1 + di, x1 = w1 + dj;
      const unsigned short* g2 = (y1 >= 0 && y1 < 64 && x1 >= 0 && x1 < 64)
          ? xTb + (((((size_t)b1_) << 12) + (y1 << 6) + x1) << 8) + c0 + coff
          : zp;
      gl2lds16(g2, AsB + 4096 + wv * 1024);
    }
    if (t < 128) {
      const unsigned short* g = Wob + (size_t)(t >> 2) * KDIM + k0 + coff;
      gl2lds16(g, BsB + wv * 1024);
    }
    __syncthreads();
    bf16x8 aF[2], bF[2];
#pragma unroll
    for (int i = 0; i < 2; ++i)
      aF[i] = *(const bf16x8*)(As + (wv * 32 + i * 16 + (lane & 15)) * 32 + (lane >> 4) * 8);
#pragma unroll
    for (int j = 0; j < 2; ++j)
      bF[j] = *(const bf16x8*)(Bs + (j * 16 + (lane & 15)) * 32 + (lane >> 4) * 8);
#pragma unroll
    for (int i = 0; i < 2; ++i)
#pragma unroll
      for (int j = 0; j < 2; ++j)
        acc[i][j] = __builtin_amdgcn_mfma_f32_16x16x32_bf16(aF[i], bF[j], acc[i][j], 0, 0, 0);
    __syncthreads();
  }

  int quad = lane >> 4, cl = lane & 15;
#pragma unroll
  for (int i = 0; i < 2; ++i)
#pragma unroll
    for (int j = 0; j < 2; ++j)
#pragma unroll
      for (int r = 0; r < 4; ++r) {
        int row = n0 + wv * 32 + i * 16 + quad * 4 + r;
        int col = j * 16 + cl;
        O2[(size_t)row * 32 + col] = acc[i][j][r];
      }
}

// ---------------------------------------------------------------------------
// Kernel 4: deformable bilinear sampler.
//  One wave per (bhw, k). Block = 576 threads = 9 waves = all k for one bhw.
//  S[bhw][k*256 + c] = bf16( bilinear(xTb, py, px)[c] * sigmoid(mask) )
// ---------------------------------------------------------------------------
__global__ __launch_bounds__(576) void k_sampler(const unsigned short* __restrict__ xTb,
                                                 const float* __restrict__ O2,
                                                 const float* __restrict__ offb,
                                                 unsigned short* __restrict__ S) {
  int t = threadIdx.x;
  int k = t >> 6, lane = t & 63;
  int bhw = blockIdx.x;
  int b = bhw >> 12, hw = bhw & 4095, h = hw >> 6, w = hw & 63;

  const float* o = O2 + (size_t)bhw * 32;
  float dy = o[2 * k]     + offb[2 * k];
  float dx = o[2 * k + 1] + offb[2 * k + 1];
  float mv = o[18 + k]    + offb[18 + k];
  float mask = 1.0f / (1.0f + expf(-mv));

  float py = (float)(h - 1 + k / 3) + dy;
  float px = (float)(w - 1 + k % 3) + dx;
  float y0f = floorf(py), x0f = floorf(px);
  float wy = py - y0f, wx = px - x0f;
  int y0 = (int)y0f, x0 = (int)x0f;
  int y1 = y0 + 1, x1 = x0 + 1;

  float v00 = (y0 >= 0 && y0 < 64 && x0 >= 0 && x0 < 64) ? 1.f : 0.f;
  float v01 = (y0 >= 0 && y0 < 64 && x1 >= 0 && x1 < 64) ? 1.f : 0.f;
  float v10 = (y1 >= 0 && y1 < 64 && x0 >= 0 && x0 < 64) ? 1.f : 0.f;
  float v11 = (y1 >= 0 && y1 < 64 && x1 >= 0 && x1 < 64) ? 1.f : 0.f;
  int y0c = min(max(y0, 0), 63), y1c = min(max(y1, 0), 63);
  int x0c = min(max(x0, 0), 63), x1c = min(max(x1, 0), 63);

  float w00 = (1.f - wy) * (1.f - wx) * v00 * mask;
  float w01 = (1.f - wy) * wx * v01 * mask;
  float w10 = wy * (1.f - wx) * v10 * mask;
  float w11 = wy * wx * v11 * mask;

  size_t base = ((size_t)b) << 20;
  int c = lane * 4;
  const ushort4 g00 = *(const ushort4*)(xTb + base + ((((size_t)y0c << 6) + x0c) << 8) + c);
  const ushort4 g01 = *(const ushort4*)(xTb + base + ((((size_t)y0c << 6) + x1c) << 8) + c);
  const ushort4 g10 = *(const ushort4*)(xTb + base + ((((size_t)y1c << 6) + x0c) << 8) + c);
  const ushort4 g11 = *(const ushort4*)(xTb + base + ((((size_t)y1c << 6) + x1c) << 8) + c);

  float s0 = w00 * bf2f(g00.x) + w01 * bf2f(g01.x) + w10 * bf2f(g10.x) + w11 * bf2f(g11.x);
  float s1 = w00 * bf2f(g00.y) + w01 * bf2f(g01.y) + w10 * bf2f(g10.y) + w11 * bf2f(g11.y);
  float s2 = w00 * bf2f(g00.z) + w01 * bf2f(g01.z) + w10 * bf2f(g10.z) + w11 * bf2f(g11.z);
  float s3 = w00 * bf2f(g00.w) + w01 * bf2f(g01.w) + w10 * bf2f(g10.w) + w11 * bf2f(g11.w);

  ushort4 r;
  r.x = f2bf(s0); r.y = f2bf(s1); r.z = f2bf(s2); r.w = f2bf(s3);
  *(ushort4*)(S + (size_t)bhw * KDIM + k * 256 + c) = r;
}

// ---------------------------------------------------------------------------
// Kernel 5: main GEMM.  out[(b,o,hw)] = sum_k Wb[o][k] * S[bhw][k]
//  M=256 (o), N=16384 (bhw), K=2304. Tile 128x128xBK32, 256 thr (4 waves 2x2).
// ---------------------------------------------------------------------------
__global__ __launch_bounds__(256) void k_main_gemm(const unsigned short* __restrict__ Wb,
                                                   const unsigned short* __restrict__ S,
                                                   float* __restrict__ out) {
  __shared__ unsigned short As[128 * 32];
  __shared__ unsigned short Bs[128 * 32];
  int t = threadIdx.x;
  int wv = t >> 6, lane = t & 63;
  int n0 = blockIdx.x * 128;
  int m0 = blockIdx.y * 128;
  int r0 = t >> 2, coff = (t & 3) * 8;
  int wr = wv >> 1, wc = wv & 1;

  f32x4 acc[4][4] = {};
  const unsigned short* gA0 = Wb + (size_t)(m0 + r0) * KDIM + coff;
  const unsigned short* gA1 = Wb + (size_t)(m0 + r0 + 64) * KDIM + coff;
  const unsigned short* gB0 = S + (size_t)(n0 + r0) * KDIM + coff;
  const unsigned short* gB1 = S + (size_t)(n0 + r0 + 64) * KDIM + coff;
  char* AsB = (char*)As;
  char* BsB = (char*)Bs;

  for (int kt = 0; kt < 72; ++kt) {
    int k0 = kt * 32;
    gl2lds16(gA0 + k0, AsB + wv * 1024);
    gl2lds16(gA1 + k0, AsB + 4096 + wv * 1024);
    gl2lds16(gB0 + k0, BsB + wv * 1024);
    gl2lds16(gB1 + k0, BsB + 4096 + wv * 1024);
    __syncthreads();
    bf16x8 aF[4], bF[4];
#pragma unroll
    for (int i = 0; i < 4; ++i)
      aF[i] = *(const bf16x8*)(As + (wr * 64 + i * 16 + (lane & 15)) * 32 + (lane >> 4) * 8);
#pragma unroll
    for (int j = 0; j < 4; ++j)
      bF[j] = *(const bf16x8*)(Bs + (wc * 64 + j * 16 + (lane & 15)) * 32 + (lane >> 4) * 8);
#pragma unroll
    for (int i = 0; i < 4; ++i)
#pragma unroll
      for (int j = 0; j < 4; ++j)
        acc[i][j] = __builtin_amdgcn_mfma_f32_16x16x32_bf16(aF[i], bF[j], acc[i][j], 0, 0, 0);
    __syncthreads();
  }

  int quad = lane >> 4, cl = lane & 15;
#pragma unroll
  for (int i = 0; i < 4; ++i) {
    int mbase = m0 + wr * 64 + i * 16 + quad * 4;
#pragma unroll
    for (int j = 0; j < 4; ++j) {
      int ncol = n0 + wc * 64 + j * 16 + cl;
      int b = ncol >> 12, hw = ncol & 4095;
      float* op = out + (((size_t)b) << 20) + hw;
#pragma unroll
      for (int r = 0; r < 4; ++r) {
        op[((size_t)(mbase + r)) << 12] = acc[i][j][r];
      }
    }
  }
}

// ---------------------------------------------------------------------------
extern "C" void kernel_launch(void* const* d_in, const int* in_sizes, int n_in,
                              void* d_out, int out_size, void* d_ws, size_t ws_size,
                              hipStream_t stream) {
  const float* x        = (const float*)d_in[0];
  const float* offset_w = (const float*)d_in[1];
  const float* offset_b = (const float*)d_in[2];
  const float* dcn_w    = (const float*)d_in[3];
  float* out = (float*)d_out;

  char* ws = (char*)d_ws;
  size_t off = 0;
  auto carve = [&](size_t bytes) -> void* {
    void* p = ws + off;
    off += (bytes + 255) & ~(size_t)255;
    return p;
  };
  unsigned short* xTb = (unsigned short*)carve(4ull * 64 * 64 * 256 * 2);   // 8 MB
  unsigned short* Wb  = (unsigned short*)carve(256ull * KDIM * 2);          // 1.125 MB
  unsigned short* Wob = (unsigned short*)carve(32ull * KDIM * 2);           // 144 KB
  unsigned short* zp  = (unsigned short*)carve(256);                        // zero page
  float*          O2  = (float*)carve(16384ull * 32 * 4);                   // 2 MB
  unsigned short* S   = (unsigned short*)carve(16384ull * (size_t)KDIM * 2);// 72 MB
  (void)ws_size; (void)in_sizes; (void)n_in; (void)out_size;

  k_transpose<<<dim3(128, 8, 4), 256, 0, stream>>>(x, xTb);
  k_wprep<<<dim3((256 * KDIM + 32 * KDIM + 128 + 255) / 256), 256, 0, stream>>>(
      dcn_w, offset_w, Wb, Wob, zp);
  k_offs_gemm<<<dim3(128), 256, 0, stream>>>(xTb, Wob, zp, O2);
  k_sampler<<<dim3(16384), 576, 0, stream>>>(xTb, O2, offset_b, S);
  k_main_gemm<<<dim3(128, 2), 256, 0, stream>>>(Wb, S, out);
}

// Round 2
// 182.026 us; speedup vs baseline: 1.0941x; 1.0941x over previous
//
#include <hip/hip_runtime.h>
#include <stdint.h>
#include <math.h>

#define KDIM 2304   // 9 * 256

typedef __attribute__((ext_vector_type(8))) short bf16x8;
typedef __attribute__((ext_vector_type(4))) float f32x4;

__device__ inline unsigned short f2bf(float f) {
  union { float f; unsigned int u; } v; v.f = f;
  unsigned int u = v.u;
  unsigned int r = (u + 0x7FFFu + ((u >> 16) & 1u)) >> 16;
  return (unsigned short)r;
}
__device__ inline float bf2f(unsigned short h) {
  union { unsigned int u; float f; } v; v.u = ((unsigned int)h) << 16;
  return v.f;
}

__device__ inline void gl2lds16(const void* g, void* l) {
  __builtin_amdgcn_global_load_lds((const __attribute__((address_space(1))) void*)g,
                                   (__attribute__((address_space(3))) void*)l,
                                   16, 0, 0);
}

// ---------------------------------------------------------------------------
// Kernel 1: x (B,C,H,W) fp32 -> xTb (B,H,W,C) bf16
// ---------------------------------------------------------------------------
__global__ __launch_bounds__(256) void k_transpose(const float* __restrict__ x,
                                                   unsigned short* __restrict__ xTb) {
  __shared__ float tile[32][33];
  int t = threadIdx.x;
  int tx = t & 31, ty = t >> 5;            // ty in [0,8)
  int p0 = blockIdx.x * 32;                // spatial (h*64+w) tile
  int c0 = blockIdx.y * 32;                // channel tile
  int b  = blockIdx.z;
  const float* xb = x + ((size_t)b << 20); // 256*4096
#pragma unroll
  for (int i = 0; i < 4; ++i) {
    int c = c0 + ty + i * 8;
    tile[ty + i * 8][tx] = xb[((size_t)c << 12) + p0 + tx];
  }
  __syncthreads();
  unsigned short* ob = xTb + ((size_t)b << 20);
#pragma unroll
  for (int i = 0; i < 4; ++i) {
    int p = p0 + ty + i * 8;
    ob[(((size_t)p) << 8) + c0 + tx] = f2bf(tile[tx][ty + i * 8]);
  }
}

// ---------------------------------------------------------------------------
// Kernel 2: weight prep.
// ---------------------------------------------------------------------------
__global__ __launch_bounds__(256) void k_wprep(const float* __restrict__ dcn_w,
                                               const float* __restrict__ offset_w,
                                               unsigned short* __restrict__ Wb,
                                               unsigned short* __restrict__ Wob,
                                               unsigned short* __restrict__ zp) {
  int gid = blockIdx.x * 256 + threadIdx.x;
  const int N1 = 256 * KDIM;
  const int N2 = 32 * KDIM;
  if (gid < N1) {
    int o = gid / KDIM, k = gid % KDIM;
    int kidx = k >> 8, c = k & 255;
    Wb[gid] = f2bf(dcn_w[((size_t)(o * 256 + c)) * 9 + kidx]);
  } else if (gid < N1 + N2) {
    int g = gid - N1;
    int ch = g / KDIM, k = g % KDIM;
    int kidx = k >> 8, c = k & 255;
    Wob[g] = (ch < 27) ? f2bf(offset_w[((size_t)(ch * 256 + c)) * 9 + kidx])
                       : (unsigned short)0;
  } else if (gid < N1 + N2 + 128) {
    zp[gid - N1 - N2] = 0;
  }
}

// ---------------------------------------------------------------------------
// Kernel 3: offset conv as MFMA GEMM with implicit im2col.
//  O2[bhw][32] = sum_k Patch[bhw][k] * Wob[ch][k]
//  Tile: BM=64 (bhw) x BN=32 (ch) x BK=32. Grid: 256 blocks, 256 thr.
//  Wave wv computes rows wv*16..wv*16+15 (acc 1x2).
// ---------------------------------------------------------------------------
__global__ __launch_bounds__(256) void k_offs_gemm(const unsigned short* __restrict__ xTb,
                                                   const unsigned short* __restrict__ Wob,
                                                   const unsigned short* __restrict__ zp,
                                                   float* __restrict__ O2) {
  __shared__ unsigned short As[64 * 32];
  __shared__ unsigned short Bs[32 * 32];
  int t = threadIdx.x;
  int wv = t >> 6, lane = t & 63;
  int n0 = blockIdx.x * 64;
  int r0 = t >> 2, coff = (t & 3) * 8;

  int rowA = n0 + r0;
  int b_ = rowA >> 12, hw = rowA & 4095, h = hw >> 6, w = hw & 63;

  f32x4 acc[2] = {};
  char* AsB = (char*)As;
  char* BsB = (char*)Bs;

  for (int kt = 0; kt < 72; ++kt) {
    int k0 = kt * 32;
    int kidx = k0 >> 8, c0 = k0 & 255;
    int di = kidx / 3 - 1, dj = kidx % 3 - 1;
    {
      int y = h + di, xx = w + dj;
      const unsigned short* g = (y >= 0 && y < 64 && xx >= 0 && xx < 64)
          ? xTb + (((((size_t)b_) << 12) + (y << 6) + xx) << 8) + c0 + coff
          : zp;
      gl2lds16(g, AsB + wv * 1024);
    }
    if (t < 128) {
      const unsigned short* g = Wob + (size_t)(t >> 2) * KDIM + k0 + coff;
      gl2lds16(g, BsB + wv * 1024);
    }
    __syncthreads();
    bf16x8 aF, bF[2];
    aF = *(const bf16x8*)(As + (wv * 16 + (lane & 15)) * 32 + (lane >> 4) * 8);
#pragma unroll
    for (int j = 0; j < 2; ++j)
      bF[j] = *(const bf16x8*)(Bs + (j * 16 + (lane & 15)) * 32 + (lane >> 4) * 8);
#pragma unroll
    for (int j = 0; j < 2; ++j)
      acc[j] = __builtin_amdgcn_mfma_f32_16x16x32_bf16(aF, bF[j], acc[j], 0, 0, 0);
    __syncthreads();
  }

  int quad = lane >> 4, cl = lane & 15;
#pragma unroll
  for (int j = 0; j < 2; ++j)
#pragma unroll
    for (int r = 0; r < 4; ++r) {
      int row = n0 + wv * 16 + quad * 4 + r;
      int col = j * 16 + cl;
      O2[(size_t)row * 32 + col] = acc[j][r];
    }
}

// ---------------------------------------------------------------------------
// Kernel 4: deformable bilinear sampler (unchanged).
// ---------------------------------------------------------------------------
__global__ __launch_bounds__(576) void k_sampler(const unsigned short* __restrict__ xTb,
                                                 const float* __restrict__ O2,
                                                 const float* __restrict__ offb,
                                                 unsigned short* __restrict__ S) {
  int t = threadIdx.x;
  int k = t >> 6, lane = t & 63;
  int bhw = blockIdx.x;
  int b = bhw >> 12, hw = bhw & 4095, h = hw >> 6, w = hw & 63;

  const float* o = O2 + (size_t)bhw * 32;
  float dy = o[2 * k]     + offb[2 * k];
  float dx = o[2 * k + 1] + offb[2 * k + 1];
  float mv = o[18 + k]    + offb[18 + k];
  float mask = 1.0f / (1.0f + expf(-mv));

  float py = (float)(h - 1 + k / 3) + dy;
  float px = (float)(w - 1 + k % 3) + dx;
  float y0f = floorf(py), x0f = floorf(px);
  float wy = py - y0f, wx = px - x0f;
  int y0 = (int)y0f, x0 = (int)x0f;
  int y1 = y0 + 1, x1 = x0 + 1;

  float v00 = (y0 >= 0 && y0 < 64 && x0 >= 0 && x0 < 64) ? 1.f : 0.f;
  float v01 = (y0 >= 0 && y0 < 64 && x1 >= 0 && x1 < 64) ? 1.f : 0.f;
  float v10 = (y1 >= 0 && y1 < 64 && x0 >= 0 && x0 < 64) ? 1.f : 0.f;
  float v11 = (y1 >= 0 && y1 < 64 && x1 >= 0 && x1 < 64) ? 1.f : 0.f;
  int y0c = min(max(y0, 0), 63), y1c = min(max(y1, 0), 63);
  int x0c = min(max(x0, 0), 63), x1c = min(max(x1, 0), 63);

  float w00 = (1.f - wy) * (1.f - wx) * v00 * mask;
  float w01 = (1.f - wy) * wx * v01 * mask;
  float w10 = wy * (1.f - wx) * v10 * mask;
  float w11 = wy * wx * v11 * mask;

  size_t base = ((size_t)b) << 20;
  int c = lane * 4;
  const ushort4 g00 = *(const ushort4*)(xTb + base + ((((size_t)y0c << 6) + x0c) << 8) + c);
  const ushort4 g01 = *(const ushort4*)(xTb + base + ((((size_t)y0c << 6) + x1c) << 8) + c);
  const ushort4 g10 = *(const ushort4*)(xTb + base + ((((size_t)y1c << 6) + x0c) << 8) + c);
  const ushort4 g11 = *(const ushort4*)(xTb + base + ((((size_t)y1c << 6) + x1c) << 8) + c);

  float s0 = w00 * bf2f(g00.x) + w01 * bf2f(g01.x) + w10 * bf2f(g10.x) + w11 * bf2f(g11.x);
  float s1 = w00 * bf2f(g00.y) + w01 * bf2f(g01.y) + w10 * bf2f(g10.y) + w11 * bf2f(g11.y);
  float s2 = w00 * bf2f(g00.z) + w01 * bf2f(g01.z) + w10 * bf2f(g10.z) + w11 * bf2f(g11.z);
  float s3 = w00 * bf2f(g00.w) + w01 * bf2f(g01.w) + w10 * bf2f(g10.w) + w11 * bf2f(g11.w);

  ushort4 r;
  r.x = f2bf(s0); r.y = f2bf(s1); r.z = f2bf(s2); r.w = f2bf(s3);
  *(ushort4*)(S + (size_t)bhw * KDIM + k * 256 + c) = r;
}

// ---------------------------------------------------------------------------
// Kernel 5: main GEMM.  out[(b,o,hw)] = sum_k Wb[o][k] * S[bhw][k]
//  M=256 (o), N=16384 (bhw), K=2304.
//  Tile BM=64 x BN=128 x BK=32. Grid (128,4) = 512 blocks, 256 thr.
//  Wave grid 2(m) x 2(n); wave = 32x64 (acc 2x4).
// ---------------------------------------------------------------------------
__global__ __launch_bounds__(256) void k_main_gemm(const unsigned short* __restrict__ Wb,
                                                   const unsigned short* __restrict__ S,
                                                   float* __restrict__ out) {
  __shared__ unsigned short As[64 * 32];    // Wb tile
  __shared__ unsigned short Bs[128 * 32];   // S tile
  int t = threadIdx.x;
  int wv = t >> 6, lane = t & 63;
  int n0 = blockIdx.x * 128;
  int m0 = blockIdx.y * 64;
  int r0 = t >> 2, coff = (t & 3) * 8;
  int wr = wv >> 1, wc = wv & 1;

  f32x4 acc[2][4] = {};
  const unsigned short* gA  = Wb + (size_t)(m0 + r0) * KDIM + coff;
  const unsigned short* gB0 = S + (size_t)(n0 + r0) * KDIM + coff;
  const unsigned short* gB1 = S + (size_t)(n0 + r0 + 64) * KDIM + coff;
  char* AsB = (char*)As;
  char* BsB = (char*)Bs;

  for (int kt = 0; kt < 72; ++kt) {
    int k0 = kt * 32;
    gl2lds16(gA + k0, AsB + wv * 1024);
    gl2lds16(gB0 + k0, BsB + wv * 1024);
    gl2lds16(gB1 + k0, BsB + 4096 + wv * 1024);
    __syncthreads();
    bf16x8 aF[2], bF[4];
#pragma unroll
    for (int i = 0; i < 2; ++i)
      aF[i] = *(const bf16x8*)(As + (wr * 32 + i * 16 + (lane & 15)) * 32 + (lane >> 4) * 8);
#pragma unroll
    for (int j = 0; j < 4; ++j)
      bF[j] = *(const bf16x8*)(Bs + (wc * 64 + j * 16 + (lane & 15)) * 32 + (lane >> 4) * 8);
#pragma unroll
    for (int i = 0; i < 2; ++i)
#pragma unroll
      for (int j = 0; j < 4; ++j)
        acc[i][j] = __builtin_amdgcn_mfma_f32_16x16x32_bf16(aF[i], bF[j], acc[i][j], 0, 0, 0);
    __syncthreads();
  }

  int quad = lane >> 4, cl = lane & 15;
#pragma unroll
  for (int i = 0; i < 2; ++i) {
    int mbase = m0 + wr * 32 + i * 16 + quad * 4;
#pragma unroll
    for (int j = 0; j < 4; ++j) {
      int ncol = n0 + wc * 64 + j * 16 + cl;
      int b = ncol >> 12, hw = ncol & 4095;
      float* op = out + (((size_t)b) << 20) + hw;
#pragma unroll
      for (int r = 0; r < 4; ++r) {
        op[((size_t)(mbase + r)) << 12] = acc[i][j][r];
      }
    }
  }
}

// ---------------------------------------------------------------------------
extern "C" void kernel_launch(void* const* d_in, const int* in_sizes, int n_in,
                              void* d_out, int out_size, void* d_ws, size_t ws_size,
                              hipStream_t stream) {
  const float* x        = (const float*)d_in[0];
  const float* offset_w = (const float*)d_in[1];
  const float* offset_b = (const float*)d_in[2];
  const float* dcn_w    = (const float*)d_in[3];
  float* out = (float*)d_out;

  char* ws = (char*)d_ws;
  size_t off = 0;
  auto carve = [&](size_t bytes) -> void* {
    void* p = ws + off;
    off += (bytes + 255) & ~(size_t)255;
    return p;
  };
  unsigned short* xTb = (unsigned short*)carve(4ull * 64 * 64 * 256 * 2);   // 8 MB
  unsigned short* Wb  = (unsigned short*)carve(256ull * KDIM * 2);          // 1.125 MB
  unsigned short* Wob = (unsigned short*)carve(32ull * KDIM * 2);           // 144 KB
  unsigned short* zp  = (unsigned short*)carve(256);                        // zero page
  float*          O2  = (float*)carve(16384ull * 32 * 4);                   // 2 MB
  unsigned short* S   = (unsigned short*)carve(16384ull * (size_t)KDIM * 2);// 72 MB
  (void)ws_size; (void)in_sizes; (void)n_in; (void)out_size;

  k_transpose<<<dim3(128, 8, 4), 256, 0, stream>>>(x, xTb);
  k_wprep<<<dim3((256 * KDIM + 32 * KDIM + 128 + 255) / 256), 256, 0, stream>>>(
      dcn_w, offset_w, Wb, Wob, zp);
  k_offs_gemm<<<dim3(256), 256, 0, stream>>>(xTb, Wob, zp, O2);
  k_sampler<<<dim3(16384), 576, 0, stream>>>(xTb, O2, offset_b, S);
  k_main_gemm<<<dim3(128, 4), 256, 0, stream>>>(Wb, S, out);
}